// Round 1
// baseline (144.906 us; speedup 1.0000x reference)
//
#include <hip/hip_runtime.h>

// CVXPolicy_Quadcopter: fused MLP (13->100 tanh ->12) + closed-form argmin via
// Lambert W. One thread per batch element; weights read via (expected) scalar
// loads; z read as 3x float4; out written as float4.
//
// Only p[6..11] are needed:
//   c = [2*(p6+p7+p8), p9, p10, p11];  x = ||c||^2
//   w solves w e^w = x (Newton from log1p(x));  u* = -c * exp(-0.5 w)

constexpr int S = 12;   // z features
constexpr int H = 100;  // hidden

__device__ __forceinline__ float fast_rcp(float x) {
    return __builtin_amdgcn_rcpf(x);
}

__global__ __launch_bounds__(256) void cvx_quad_kernel(
    const float* __restrict__ z, const float* __restrict__ t,
    const float* __restrict__ W1, const float* __restrict__ b1,
    const float* __restrict__ W2, const float* __restrict__ b2,
    float* __restrict__ out, int B)
{
    int i = blockIdx.x * 256 + threadIdx.x;
    if (i >= B) return;

    // Load input row: [t, z0..z11]
    float inp[S + 1];
    inp[0] = t[i];
    const float4* zr = reinterpret_cast<const float4*>(z) + (size_t)i * 3;
    float4 a0 = zr[0];
    float4 a1 = zr[1];
    float4 a2 = zr[2];
    inp[1]  = a0.x; inp[2]  = a0.y; inp[3]  = a0.z; inp[4]  = a0.w;
    inp[5]  = a1.x; inp[6]  = a1.y; inp[7]  = a1.z; inp[8]  = a1.w;
    inp[9]  = a2.x; inp[10] = a2.y; inp[11] = a2.z; inp[12] = a2.w;

    // Accumulators for p[6..11]
    float p6  = b2[6],  p7  = b2[7],  p8  = b2[8];
    float p9  = b2[9],  p10 = b2[10], p11 = b2[11];

    #pragma unroll
    for (int j = 0; j < H; ++j) {
        float acc = b1[j];
        #pragma unroll
        for (int k = 0; k < S + 1; ++k) {
            acc = fmaf(inp[k], W1[k * H + j], acc);
        }
        // tanh(acc) = sign(acc) * (1 - e) / (1 + e),  e = exp(-2|acc|)
        float e  = __expf(-2.0f * fabsf(acc));
        float th = (1.0f - e) * fast_rcp(1.0f + e);
        th = __builtin_copysignf(th, acc);

        const float* w2r = W2 + j * S;
        p6  = fmaf(th, w2r[6],  p6);
        p7  = fmaf(th, w2r[7],  p7);
        p8  = fmaf(th, w2r[8],  p8);
        p9  = fmaf(th, w2r[9],  p9);
        p10 = fmaf(th, w2r[10], p10);
        p11 = fmaf(th, w2r[11], p11);
    }

    float c0 = 2.0f * (p6 + p7 + p8);  // / MASS, MASS = 0.5
    float c1 = p9, c2 = p10, c3 = p11;
    float x = fmaf(c0, c0, fmaf(c1, c1, fmaf(c2, c2, c3 * c3)));

    // Lambert W: solve w e^w = x, Newton from w0 = log(1+x)
    float w = __logf(1.0f + x);
    #pragma unroll
    for (int it = 0; it < 8; ++it) {
        float ew  = __expf(w);
        float num = fmaf(w, ew, -x);        // w*e^w - x
        float den = fmaf(ew, w, ew);        // e^w * (w + 1)
        w = w - num * fast_rcp(den);
    }

    float sc = -__expf(-0.5f * w);
    float4 o;
    o.x = c0 * sc;
    o.y = c1 * sc;
    o.z = c2 * sc;
    o.w = c3 * sc;
    reinterpret_cast<float4*>(out)[i] = o;
}

extern "C" void kernel_launch(void* const* d_in, const int* in_sizes, int n_in,
                              void* d_out, int out_size, void* d_ws, size_t ws_size,
                              hipStream_t stream) {
    const float* z  = (const float*)d_in[0];
    const float* t  = (const float*)d_in[1];
    const float* W1 = (const float*)d_in[2];
    const float* b1 = (const float*)d_in[3];
    const float* W2 = (const float*)d_in[4];
    const float* b2 = (const float*)d_in[5];
    float* out = (float*)d_out;

    int B = in_sizes[1];  // t has B elements
    int grid = (B + 255) / 256;
    cvx_quad_kernel<<<dim3(grid), dim3(256), 0, stream>>>(z, t, W1, b1, W2, b2, out, B);
}

// Round 2
// 116.011 us; speedup vs baseline: 1.2491x; 1.2491x over previous
//
#include <hip/hip_runtime.h>

// CVXPolicy_Quadcopter: fused MLP (13->100 tanh ->12) + closed-form argmin via
// Lambert W. 2 batch elements per thread; j-loop kept rolled (unroll 2) so the
// body stays I-cache-resident and weights stream through scalar loads.
//
// Only p[6..11] are needed:
//   c = [2*(p6+p7+p8), p9, p10, p11];  x = ||c||^2
//   w solves w e^w = x (Newton from log1p(x));  u* = -c * exp(-0.5 w)

constexpr int S = 12;   // z features
constexpr int H = 100;  // hidden

__device__ __forceinline__ float fast_rcp(float x) {
    return __builtin_amdgcn_rcpf(x);
}

// tanh(x) = 1 - 2/(1 + e^{2x});  stable at both tails (rcp(inf)=0)
__device__ __forceinline__ float fast_tanh(float x) {
    float e = __expf(2.0f * x);
    return fmaf(-2.0f, fast_rcp(1.0f + e), 1.0f);
}

__global__ __launch_bounds__(256) void cvx_quad_kernel(
    const float* __restrict__ z, const float* __restrict__ t,
    const float* __restrict__ W1, const float* __restrict__ b1,
    const float* __restrict__ W2, const float* __restrict__ b2,
    float* __restrict__ out, int B)
{
    int tid = blockIdx.x * 256 + threadIdx.x;
    int i0 = tid * 2;
    if (i0 >= B) return;

    // Load two input rows: [t, z0..z11] each
    float inpA[S + 1], inpB[S + 1];
    inpA[0] = t[i0];
    inpB[0] = t[i0 + 1];
    const float4* zr = reinterpret_cast<const float4*>(z) + (size_t)i0 * 3;
    float4 a0 = zr[0], a1 = zr[1], a2 = zr[2];
    float4 c0v = zr[3], c1v = zr[4], c2v = zr[5];
    inpA[1]  = a0.x; inpA[2]  = a0.y; inpA[3]  = a0.z; inpA[4]  = a0.w;
    inpA[5]  = a1.x; inpA[6]  = a1.y; inpA[7]  = a1.z; inpA[8]  = a1.w;
    inpA[9]  = a2.x; inpA[10] = a2.y; inpA[11] = a2.z; inpA[12] = a2.w;
    inpB[1]  = c0v.x; inpB[2]  = c0v.y; inpB[3]  = c0v.z; inpB[4]  = c0v.w;
    inpB[5]  = c1v.x; inpB[6]  = c1v.y; inpB[7]  = c1v.z; inpB[8]  = c1v.w;
    inpB[9]  = c2v.x; inpB[10] = c2v.y; inpB[11] = c2v.z; inpB[12] = c2v.w;

    // Accumulators for p[6..11], both elements
    float pA[6], pB[6];
    #pragma unroll
    for (int m = 0; m < 6; ++m) {
        float bm = b2[6 + m];
        pA[m] = bm;
        pB[m] = bm;
    }

    #pragma unroll 2
    for (int j = 0; j < H; ++j) {
        float accA = b1[j];
        float accB = accA;
        const float* w1c = W1 + j;              // column j, row-stride H
        #pragma unroll
        for (int k = 0; k < S + 1; ++k) {
            float w = w1c[k * H];               // wave-uniform -> s_load
            accA = fmaf(inpA[k], w, accA);
            accB = fmaf(inpB[k], w, accB);
        }
        float thA = fast_tanh(accA);
        float thB = fast_tanh(accB);
        const float* w2r = W2 + j * S + 6;
        #pragma unroll
        for (int m = 0; m < 6; ++m) {
            float w = w2r[m];                   // wave-uniform -> s_load
            pA[m] = fmaf(thA, w, pA[m]);
            pB[m] = fmaf(thB, w, pB[m]);
        }
    }

    #pragma unroll
    for (int e = 0; e < 2; ++e) {
        const float* p = e ? pB : pA;
        float c0 = 2.0f * (p[0] + p[1] + p[2]);  // / MASS, MASS = 0.5
        float c1 = p[3], c2 = p[4], c3 = p[5];
        float x = fmaf(c0, c0, fmaf(c1, c1, fmaf(c2, c2, c3 * c3)));

        // Lambert W: solve w e^w = x, Newton from w0 = log(1+x)
        float w = __logf(1.0f + x);
        #pragma unroll
        for (int it = 0; it < 6; ++it) {
            float ew  = __expf(w);
            float num = fmaf(w, ew, -x);        // w*e^w - x
            float den = fmaf(ew, w, ew);        // e^w * (w + 1)
            w = w - num * fast_rcp(den);
        }

        float sc = -__expf(-0.5f * w);
        float4 o;
        o.x = c0 * sc;
        o.y = c1 * sc;
        o.z = c2 * sc;
        o.w = c3 * sc;
        reinterpret_cast<float4*>(out)[i0 + e] = o;
    }
}

extern "C" void kernel_launch(void* const* d_in, const int* in_sizes, int n_in,
                              void* d_out, int out_size, void* d_ws, size_t ws_size,
                              hipStream_t stream) {
    const float* z  = (const float*)d_in[0];
    const float* t  = (const float*)d_in[1];
    const float* W1 = (const float*)d_in[2];
    const float* b1 = (const float*)d_in[3];
    const float* W2 = (const float*)d_in[4];
    const float* b2 = (const float*)d_in[5];
    float* out = (float*)d_out;

    int B = in_sizes[1];  // t has B elements
    int threads = (B + 1) / 2;
    int grid = (threads + 255) / 256;
    cvx_quad_kernel<<<dim3(grid), dim3(256), 0, stream>>>(z, t, W1, b1, W2, b2, out, B);
}